// Round 1
// baseline (167.922 us; speedup 1.0000x reference)
//
#include <hip/hip_runtime.h>
#include <math.h>

#define NB 8
#define MSEG 16
#define PPIX (640*640)
#define PV4 (PPIX/4)
#define DELTA_AGG 0.5f
#define DELTA_DIS 3.0f

// workspace float layout
#define OFF_CNT_K 0
#define OFF_CNT_T (NB*MSEG)            // 128
#define OFF_G     (2*NB*MSEG)          // 256 (N*M*4 = 512 floats; Gsum then finalized G in place)
#define OFF_LSUM  (6*NB*MSEG)          // 768
#define WS_FLOATS (7*NB*MSEG)          // 896

// ---------------- pass 1: segment sums by kern + histograms ----------------
__global__ __launch_bounds__(256) void pass1_kernel(
    const float* __restrict__ preds, const int* __restrict__ targets,
    float* __restrict__ ws) {
  const int n = blockIdx.y;
  const int tid = threadIdx.x;
  const int w = tid >> 6;  // wave id, 4 waves/block

  const float4* __restrict__ c0 = (const float4*)(preds + ((size_t)n*6 + 2)*PPIX);
  const float4* __restrict__ c1 = (const float4*)(preds + ((size_t)n*6 + 3)*PPIX);
  const float4* __restrict__ c2 = (const float4*)(preds + ((size_t)n*6 + 4)*PPIX);
  const float4* __restrict__ c3 = (const float4*)(preds + ((size_t)n*6 + 5)*PPIX);
  const int4*  __restrict__ textv = (const int4*)(targets + (size_t)n*2*PPIX);
  const int4*  __restrict__ kernv = (const int4*)(targets + ((size_t)n*2 + 1)*PPIX);

  __shared__ float s_k[4][MSEG][5];   // per-wave: 4 channel sums + count (kern)
  __shared__ float s_t[4][MSEG];      // per-wave: text counts
  for (int i = tid; i < 4*MSEG*5; i += 256) ((float*)s_k)[i] = 0.f;
  for (int i = tid; i < 4*MSEG;   i += 256) ((float*)s_t)[i] = 0.f;
  __syncthreads();

#define ACC1(K, T, AX, BX, CX, DX) do {           \
    atomicAdd(&s_k[w][(K)][0], (AX));             \
    atomicAdd(&s_k[w][(K)][1], (BX));             \
    atomicAdd(&s_k[w][(K)][2], (CX));             \
    atomicAdd(&s_k[w][(K)][3], (DX));             \
    atomicAdd(&s_k[w][(K)][4], 1.0f);             \
    atomicAdd(&s_t[w][(T)], 1.0f);                \
  } while (0)

  for (int p = blockIdx.x*256 + tid; p < PV4; p += gridDim.x*256) {
    int4 kk = kernv[p];
    int4 tt = textv[p];
    float4 a = c0[p], b = c1[p], c = c2[p], d = c3[p];
    ACC1(kk.x, tt.x, a.x, b.x, c.x, d.x);
    ACC1(kk.y, tt.y, a.y, b.y, c.y, d.y);
    ACC1(kk.z, tt.z, a.z, b.z, c.z, d.z);
    ACC1(kk.w, tt.w, a.w, b.w, c.w, d.w);
  }
#undef ACC1
  __syncthreads();

  float* cnt_k = ws + OFF_CNT_K + n*MSEG;
  float* cnt_t = ws + OFF_CNT_T + n*MSEG;
  float* Gsum  = ws + OFF_G     + (size_t)n*MSEG*4;
  if (tid < MSEG*5) {
    int m = tid / 5, f = tid % 5;
    float s = s_k[0][m][f] + s_k[1][m][f] + s_k[2][m][f] + s_k[3][m][f];
    if (f < 4) atomicAdd(&Gsum[m*4 + f], s);
    else       atomicAdd(&cnt_k[m], s);
  } else if (tid < MSEG*5 + MSEG) {
    int m = tid - MSEG*5;
    float s = s_t[0][m] + s_t[1][m] + s_t[2][m] + s_t[3][m];
    atomicAdd(&cnt_t[m], s);
  }
}

// ------------- finalize G + discrimination loss (one block/batch) -------------
__global__ __launch_bounds__(256) void finalize_dis_kernel(
    float* __restrict__ ws, float* __restrict__ out) {
  const int n = blockIdx.x;
  const int tid = threadIdx.x;
  float* cnt_k = ws + OFF_CNT_K + n*MSEG;
  float* cnt_t = ws + OFF_CNT_T + n*MSEG;
  float* G     = ws + OFF_G     + (size_t)n*MSEG*4;

  __shared__ float s_G[MSEG][4];
  __shared__ int   s_valid[MSEG];
  __shared__ int   s_nv;
  __shared__ float red[256];

  if (tid < MSEG*4) {
    int m = tid >> 2;
    float g = G[tid] / fmaxf(cnt_k[m], 1.0f);
    s_G[m][tid & 3] = g;
    G[tid] = g;  // store finalized G for pass 2
  }
  if (tid < MSEG)
    s_valid[tid] = (tid >= 1) && (cnt_k[tid] > 0.f) && (cnt_t[tid] > 0.f);
  __syncthreads();
  if (tid == 0) { int nv = 0; for (int m = 0; m < MSEG; m++) nv += s_valid[m]; s_nv = nv; }

  float lp = 0.f;
  {
    int i = tid >> 4, j = tid & 15;
    if (i != j && s_valid[i] && s_valid[j]) {
      float dx = s_G[i][0] - s_G[j][0];
      float dy = s_G[i][1] - s_G[j][1];
      float dz = s_G[i][2] - s_G[j][2];
      float dw = s_G[i][3] - s_G[j][3];
      float dist = sqrtf(dx*dx + dy*dy + dz*dz + dw*dw);
      float t = fmaxf(DELTA_DIS - dist, 0.f);
      lp = logf(t*t + 1.f);
    }
  }
  red[tid] = lp;
  __syncthreads();
  for (int s = 128; s > 0; s >>= 1) {
    if (tid < s) red[tid] += red[tid + s];
    __syncthreads();
  }
  if (tid == 0) {
    int nv = s_nv;
    float dis = 0.f;
    if (nv > 1) dis = 0.5f * red[0] / (float)(nv * (nv - 1));
    out[NB + n] = dis;
  }
}

// ---------------- pass 2: aggregation loss segment sums by text ----------------
__global__ __launch_bounds__(256) void pass2_kernel(
    const float* __restrict__ preds, const int* __restrict__ targets,
    float* __restrict__ ws) {
  const int n = blockIdx.y;
  const int tid = threadIdx.x;
  const int w = tid >> 6;

  const float4* __restrict__ c0 = (const float4*)(preds + ((size_t)n*6 + 2)*PPIX);
  const float4* __restrict__ c1 = (const float4*)(preds + ((size_t)n*6 + 3)*PPIX);
  const float4* __restrict__ c2 = (const float4*)(preds + ((size_t)n*6 + 4)*PPIX);
  const float4* __restrict__ c3 = (const float4*)(preds + ((size_t)n*6 + 5)*PPIX);
  const int4*  __restrict__ textv = (const int4*)(targets + (size_t)n*2*PPIX);
  const float* __restrict__ G = ws + OFF_G + (size_t)n*MSEG*4;

  __shared__ float4 s_G[MSEG];
  __shared__ float  s_l[4][MSEG];
  if (tid < MSEG) s_G[tid] = ((const float4*)G)[tid];
  for (int i = tid; i < 4*MSEG; i += 256) ((float*)s_l)[i] = 0.f;
  __syncthreads();

#define ACC2(T, AX, BX, CX, DX) do {                        \
    float4 g = s_G[(T)];                                    \
    float dx = (AX) - g.x, dy = (BX) - g.y;                 \
    float dz = (CX) - g.z, dw = (DX) - g.w;                 \
    float dist = sqrtf(dx*dx + dy*dy + dz*dz + dw*dw) - DELTA_AGG; \
    dist = fmaxf(dist, 0.f);                                \
    float l = logf(dist*dist + 1.f);                        \
    atomicAdd(&s_l[w][(T)], l);                             \
  } while (0)

  for (int p = blockIdx.x*256 + tid; p < PV4; p += gridDim.x*256) {
    int4 tt = textv[p];
    float4 a = c0[p], b = c1[p], c = c2[p], d = c3[p];
    ACC2(tt.x, a.x, b.x, c.x, d.x);
    ACC2(tt.y, a.y, b.y, c.y, d.y);
    ACC2(tt.z, a.z, b.z, c.z, d.z);
    ACC2(tt.w, a.w, b.w, c.w, d.w);
  }
#undef ACC2
  __syncthreads();

  if (tid < MSEG) {
    float s = s_l[0][tid] + s_l[1][tid] + s_l[2][tid] + s_l[3][tid];
    atomicAdd(&ws[OFF_LSUM + n*MSEG + tid], s);
  }
}

// ---------------- finalize aggregation loss (one wave/batch) ----------------
__global__ __launch_bounds__(64) void finalize_agg_kernel(
    const float* __restrict__ ws, float* __restrict__ out) {
  const int n = blockIdx.x;
  const int tid = threadIdx.x;
  const float* cnt_k = ws + OFF_CNT_K + n*MSEG;
  const float* cnt_t = ws + OFF_CNT_T + n*MSEG;
  const float* lsum  = ws + OFF_LSUM  + n*MSEG;

  float lm = 0.f, vc = 0.f;
  if (tid >= 1 && tid < MSEG) {
    float ck = cnt_k[tid], ct = cnt_t[tid];
    if (ck > 0.f && ct > 0.f) {
      vc = 1.f;
      lm = lsum[tid] / fmaxf(ct, 1.f);
    }
  }
  for (int off = 32; off > 0; off >>= 1) {
    lm += __shfl_down(lm, off);
    vc += __shfl_down(vc, off);
  }
  if (tid == 0) {
    int nv = (int)(vc + 0.5f);
    out[n] = lm / (float)(nv > 1 ? nv : 1);
  }
}

extern "C" void kernel_launch(void* const* d_in, const int* in_sizes, int n_in,
                              void* d_out, int out_size, void* d_ws, size_t ws_size,
                              hipStream_t stream) {
  const float* preds   = (const float*)d_in[0];
  const int*   targets = (const int*)d_in[1];
  float* out = (float*)d_out;
  float* ws  = (float*)d_ws;

  hipMemsetAsync(d_ws, 0, WS_FLOATS * sizeof(float), stream);

  dim3 grid(128, NB);
  pass1_kernel<<<grid, 256, 0, stream>>>(preds, targets, ws);
  finalize_dis_kernel<<<NB, 256, 0, stream>>>(ws, out);
  pass2_kernel<<<grid, 256, 0, stream>>>(preds, targets, ws);
  finalize_agg_kernel<<<NB, 64, 0, stream>>>(ws, out);
}

// Round 2
// 67.321 us; speedup vs baseline: 2.4943x; 2.4943x over previous
//
#include <hip/hip_runtime.h>
#include <math.h>

#define NB 8
#define MSEG 16
#define PPIX (640*640)
#define PV4 (PPIX/4)
#define DELTA_AGG 0.5f
#define DELTA_DIS 3.0f

// workspace float layout
#define OFF_CNT_K 0
#define OFF_CNT_T (NB*MSEG)            // 128
#define OFF_G     (2*NB*MSEG)          // 256 (N*M*4 = 512 floats; Gsum then finalized G in place)
#define OFF_LSUM  (6*NB*MSEG)          // 768
#define WS_FLOATS (7*NB*MSEG)          // 896

__device__ __forceinline__ float wave_sum64(float v) {
#pragma unroll
  for (int off = 32; off > 0; off >>= 1) v += __shfl_xor(v, off);
  return v;
}

// ---------------- pass 1: segment sums by kern + histograms (register bins) ----------------
__global__ __launch_bounds__(256, 2) void pass1_kernel(
    const float* __restrict__ preds, const int* __restrict__ targets,
    float* __restrict__ ws) {
  const int n = blockIdx.y;
  const int tid = threadIdx.x;

  const float4* __restrict__ c0 = (const float4*)(preds + ((size_t)n*6 + 2)*PPIX);
  const float4* __restrict__ c1 = (const float4*)(preds + ((size_t)n*6 + 3)*PPIX);
  const float4* __restrict__ c2 = (const float4*)(preds + ((size_t)n*6 + 4)*PPIX);
  const float4* __restrict__ c3 = (const float4*)(preds + ((size_t)n*6 + 5)*PPIX);
  const int4*  __restrict__ textv = (const int4*)(targets + (size_t)n*2*PPIX);
  const int4*  __restrict__ kernv = (const int4*)(targets + ((size_t)n*2 + 1)*PPIX);

  // per-thread register accumulators, statically indexed only (unrolled loops)
  float s0[MSEG], s1[MSEG], s2[MSEG], s3[MSEG], ck[MSEG], ct[MSEG];
#pragma unroll
  for (int m = 0; m < MSEG; ++m) { s0[m]=0.f; s1[m]=0.f; s2[m]=0.f; s3[m]=0.f; ck[m]=0.f; ct[m]=0.f; }

#define PIX1(K, T, A0, A1, A2, A3)                      \
  _Pragma("unroll")                                     \
  for (int m = 0; m < MSEG; ++m) {                      \
    float fk = ((K) == m) ? 1.0f : 0.0f;                \
    s0[m] = fmaf(fk, (A0), s0[m]);                      \
    s1[m] = fmaf(fk, (A1), s1[m]);                      \
    s2[m] = fmaf(fk, (A2), s2[m]);                      \
    s3[m] = fmaf(fk, (A3), s3[m]);                      \
    ck[m] += fk;                                        \
    ct[m] += ((T) == m) ? 1.0f : 0.0f;                  \
  }

  for (int p = blockIdx.x*256 + tid; p < PV4; p += gridDim.x*256) {
    int4 kk = kernv[p];
    int4 tt = textv[p];
    float4 a = c0[p], b = c1[p], c = c2[p], d = c3[p];
    PIX1(kk.x, tt.x, a.x, b.x, c.x, d.x);
    PIX1(kk.y, tt.y, a.y, b.y, c.y, d.y);
    PIX1(kk.z, tt.z, a.z, b.z, c.z, d.z);
    PIX1(kk.w, tt.w, a.w, b.w, c.w, d.w);
  }
#undef PIX1

  // wave butterfly reduce (result valid in all lanes)
#pragma unroll
  for (int m = 0; m < MSEG; ++m) {
    s0[m] = wave_sum64(s0[m]);
    s1[m] = wave_sum64(s1[m]);
    s2[m] = wave_sum64(s2[m]);
    s3[m] = wave_sum64(s3[m]);
    ck[m] = wave_sum64(ck[m]);
    ct[m] = wave_sum64(ct[m]);
  }

  __shared__ float s_red[4][96];
  const int w = tid >> 6, lane = tid & 63;
  if (lane == 0) {
#pragma unroll
    for (int m = 0; m < MSEG; ++m) {
      s_red[w][m*4 + 0] = s0[m];
      s_red[w][m*4 + 1] = s1[m];
      s_red[w][m*4 + 2] = s2[m];
      s_red[w][m*4 + 3] = s3[m];
      s_red[w][64 + m]  = ck[m];
      s_red[w][80 + m]  = ct[m];
    }
  }
  __syncthreads();
  if (tid < 96) {
    float v = s_red[0][tid] + s_red[1][tid] + s_red[2][tid] + s_red[3][tid];
    if (tid < 64)      atomicAdd(&ws[OFF_G + n*64 + tid], v);
    else if (tid < 80) atomicAdd(&ws[OFF_CNT_K + n*MSEG + (tid - 64)], v);
    else               atomicAdd(&ws[OFF_CNT_T + n*MSEG + (tid - 80)], v);
  }
}

// ------------- finalize G + discrimination loss (one block/batch) -------------
__global__ __launch_bounds__(256) void finalize_dis_kernel(
    float* __restrict__ ws, float* __restrict__ out) {
  const int n = blockIdx.x;
  const int tid = threadIdx.x;
  float* cnt_k = ws + OFF_CNT_K + n*MSEG;
  float* cnt_t = ws + OFF_CNT_T + n*MSEG;
  float* G     = ws + OFF_G     + (size_t)n*MSEG*4;

  __shared__ float s_G[MSEG][4];
  __shared__ int   s_valid[MSEG];
  __shared__ int   s_nv;
  __shared__ float red[256];

  if (tid < MSEG*4) {
    int m = tid >> 2;
    float g = G[tid] / fmaxf(cnt_k[m], 1.0f);
    s_G[m][tid & 3] = g;
    G[tid] = g;  // store finalized G for pass 2
  }
  if (tid < MSEG)
    s_valid[tid] = (tid >= 1) && (cnt_k[tid] > 0.f) && (cnt_t[tid] > 0.f);
  __syncthreads();
  if (tid == 0) { int nv = 0; for (int m = 0; m < MSEG; m++) nv += s_valid[m]; s_nv = nv; }

  float lp = 0.f;
  {
    int i = tid >> 4, j = tid & 15;
    if (i != j && s_valid[i] && s_valid[j]) {
      float dx = s_G[i][0] - s_G[j][0];
      float dy = s_G[i][1] - s_G[j][1];
      float dz = s_G[i][2] - s_G[j][2];
      float dw = s_G[i][3] - s_G[j][3];
      float dist = sqrtf(dx*dx + dy*dy + dz*dz + dw*dw);
      float t = fmaxf(DELTA_DIS - dist, 0.f);
      lp = logf(t*t + 1.f);
    }
  }
  red[tid] = lp;
  __syncthreads();
  for (int s = 128; s > 0; s >>= 1) {
    if (tid < s) red[tid] += red[tid + s];
    __syncthreads();
  }
  if (tid == 0) {
    int nv = s_nv;
    float dis = 0.f;
    if (nv > 1) dis = 0.5f * red[0] / (float)(nv * (nv - 1));
    out[NB + n] = dis;
  }
}

// ---------------- pass 2: aggregation loss segment sums by text (register bins) ----------------
__global__ __launch_bounds__(256, 2) void pass2_kernel(
    const float* __restrict__ preds, const int* __restrict__ targets,
    float* __restrict__ ws) {
  const int n = blockIdx.y;
  const int tid = threadIdx.x;

  const float4* __restrict__ c0 = (const float4*)(preds + ((size_t)n*6 + 2)*PPIX);
  const float4* __restrict__ c1 = (const float4*)(preds + ((size_t)n*6 + 3)*PPIX);
  const float4* __restrict__ c2 = (const float4*)(preds + ((size_t)n*6 + 4)*PPIX);
  const float4* __restrict__ c3 = (const float4*)(preds + ((size_t)n*6 + 5)*PPIX);
  const int4*  __restrict__ textv = (const int4*)(targets + (size_t)n*2*PPIX);

  __shared__ float4 s_G[MSEG];
  if (tid < MSEG) s_G[tid] = ((const float4*)(ws + OFF_G + (size_t)n*MSEG*4))[tid];
  __syncthreads();

  float ls[MSEG];
#pragma unroll
  for (int m = 0; m < MSEG; ++m) ls[m] = 0.f;

#define PIX2(T, A0, A1, A2, A3) do {                            \
    float4 g = s_G[(T)];                                        \
    float dx = (A0) - g.x, dy = (A1) - g.y;                     \
    float dz = (A2) - g.z, dw = (A3) - g.w;                     \
    float sq = fmaf(dx, dx, fmaf(dy, dy, fmaf(dz, dz, dw*dw))); \
    float dd = fmaxf(__fsqrt_rn(sq) - DELTA_AGG, 0.f);          \
    float l = __logf(fmaf(dd, dd, 1.f));                        \
    _Pragma("unroll")                                           \
    for (int m = 0; m < MSEG; ++m)                              \
      ls[m] += ((T) == m) ? l : 0.f;                            \
  } while (0)

  for (int p = blockIdx.x*256 + tid; p < PV4; p += gridDim.x*256) {
    int4 tt = textv[p];
    float4 a = c0[p], b = c1[p], c = c2[p], d = c3[p];
    PIX2(tt.x, a.x, b.x, c.x, d.x);
    PIX2(tt.y, a.y, b.y, c.y, d.y);
    PIX2(tt.z, a.z, b.z, c.z, d.z);
    PIX2(tt.w, a.w, b.w, c.w, d.w);
  }
#undef PIX2

#pragma unroll
  for (int m = 0; m < MSEG; ++m) ls[m] = wave_sum64(ls[m]);

  __shared__ float s_red[4][MSEG];
  const int w = tid >> 6, lane = tid & 63;
  if (lane == 0) {
#pragma unroll
    for (int m = 0; m < MSEG; ++m) s_red[w][m] = ls[m];
  }
  __syncthreads();
  if (tid < MSEG) {
    float v = s_red[0][tid] + s_red[1][tid] + s_red[2][tid] + s_red[3][tid];
    atomicAdd(&ws[OFF_LSUM + n*MSEG + tid], v);
  }
}

// ---------------- finalize aggregation loss (one wave/batch) ----------------
__global__ __launch_bounds__(64) void finalize_agg_kernel(
    const float* __restrict__ ws, float* __restrict__ out) {
  const int n = blockIdx.x;
  const int tid = threadIdx.x;
  const float* cnt_k = ws + OFF_CNT_K + n*MSEG;
  const float* cnt_t = ws + OFF_CNT_T + n*MSEG;
  const float* lsum  = ws + OFF_LSUM  + n*MSEG;

  float lm = 0.f, vc = 0.f;
  if (tid >= 1 && tid < MSEG) {
    float ck = cnt_k[tid], ct = cnt_t[tid];
    if (ck > 0.f && ct > 0.f) {
      vc = 1.f;
      lm = lsum[tid] / fmaxf(ct, 1.f);
    }
  }
  for (int off = 32; off > 0; off >>= 1) {
    lm += __shfl_down(lm, off);
    vc += __shfl_down(vc, off);
  }
  if (tid == 0) {
    int nv = (int)(vc + 0.5f);
    out[n] = lm / (float)(nv > 1 ? nv : 1);
  }
}

extern "C" void kernel_launch(void* const* d_in, const int* in_sizes, int n_in,
                              void* d_out, int out_size, void* d_ws, size_t ws_size,
                              hipStream_t stream) {
  const float* preds   = (const float*)d_in[0];
  const int*   targets = (const int*)d_in[1];
  float* out = (float*)d_out;
  float* ws  = (float*)d_ws;

  hipMemsetAsync(d_ws, 0, WS_FLOATS * sizeof(float), stream);

  dim3 grid(128, NB);
  pass1_kernel<<<grid, 256, 0, stream>>>(preds, targets, ws);
  finalize_dis_kernel<<<NB, 256, 0, stream>>>(ws, out);
  pass2_kernel<<<grid, 256, 0, stream>>>(preds, targets, ws);
  finalize_agg_kernel<<<NB, 64, 0, stream>>>(ws, out);
}